// Round 8
// baseline (450.251 us; speedup 1.0000x reference)
//
#include <hip/hip_runtime.h>
#include <math.h>

#define HDIM 1024
#define NHEAD 16
#define HEADD 64
#define SEQLEN 2048
#define BATCH 4
#define MROWS (BATCH * SEQLEN)  // 8192
#define LN_EPS 1e-5f
#define QSCALE 2.8853900817779268f  // 2 * log2(e): logits in log2 units

typedef float f32x4 __attribute__((ext_vector_type(4)));
typedef short s16x8 __attribute__((ext_vector_type(8)));
typedef short s16x4 __attribute__((ext_vector_type(4)));
typedef __bf16 bf16x4 __attribute__((ext_vector_type(4)));
typedef _Float16 f16x8 __attribute__((ext_vector_type(8)));

#define MFMA16(a, b, c) __builtin_amdgcn_mfma_f32_16x16x32_bf16((a), (b), (c), 0, 0, 0)
#define MFMA16H(a, b, c) __builtin_amdgcn_mfma_f32_16x16x32_f16((a), (b), (c), 0, 0, 0)

#if __has_builtin(__builtin_amdgcn_exp2f)
#define EXP2(x) __builtin_amdgcn_exp2f(x)
#else
#define EXP2(x) exp2f(x)
#endif

__device__ __forceinline__ void load_lds16(const __bf16* g, __bf16* l) {
  __builtin_amdgcn_global_load_lds((const __attribute__((address_space(1))) void*)g,
                                   (__attribute__((address_space(3))) void*)l, 16, 0, 0);
}

// ---------------------------------------------------------------------------
// fp32 -> bf16 (hi, lo) split, 4 elems/thread (feat)
// ---------------------------------------------------------------------------
__global__ __launch_bounds__(256) void split_k(const float* __restrict__ src,
                                               __bf16* __restrict__ h,
                                               __bf16* __restrict__ l, int n4) {
  int i = blockIdx.x * blockDim.x + threadIdx.x;
  if (i >= n4) return;
  float4 v = reinterpret_cast<const float4*>(src)[i];
  bf16x4 hv, lv;
  hv[0] = (__bf16)v.x; hv[1] = (__bf16)v.y; hv[2] = (__bf16)v.z; hv[3] = (__bf16)v.w;
  lv[0] = (__bf16)(v.x - (float)hv[0]);
  lv[1] = (__bf16)(v.y - (float)hv[1]);
  lv[2] = (__bf16)(v.z - (float)hv[2]);
  lv[3] = (__bf16)(v.w - (float)hv[3]);
  reinterpret_cast<bf16x4*>(h)[i] = hv;
  reinterpret_cast<bf16x4*>(l)[i] = lv;
}

// All 4 weight matrices in one launch (blockIdx.y selects matrix).
__global__ __launch_bounds__(256) void wsplit_k(
    const float* __restrict__ w0, const float* __restrict__ w1,
    const float* __restrict__ w2, const float* __restrict__ w3,
    __bf16* __restrict__ h0, __bf16* __restrict__ l0, __bf16* __restrict__ h1,
    __bf16* __restrict__ l1, __bf16* __restrict__ h2, __bf16* __restrict__ l2,
    __bf16* __restrict__ h3, __bf16* __restrict__ l3) {
  const int which = blockIdx.y;
  const float* src = which == 0 ? w0 : which == 1 ? w1 : which == 2 ? w2 : w3;
  __bf16* h = which == 0 ? h0 : which == 1 ? h1 : which == 2 ? h2 : h3;
  __bf16* l = which == 0 ? l0 : which == 1 ? l1 : which == 2 ? l2 : l3;
  const int i = blockIdx.x * blockDim.x + threadIdx.x;
  float4 v = reinterpret_cast<const float4*>(src)[i];
  bf16x4 hv, lv;
  hv[0] = (__bf16)v.x; hv[1] = (__bf16)v.y; hv[2] = (__bf16)v.z; hv[3] = (__bf16)v.w;
  lv[0] = (__bf16)(v.x - (float)hv[0]);
  lv[1] = (__bf16)(v.y - (float)hv[1]);
  lv[2] = (__bf16)(v.z - (float)hv[2]);
  lv[3] = (__bf16)(v.w - (float)hv[3]);
  reinterpret_cast<bf16x4*>(h)[i] = hv;
  reinterpret_cast<bf16x4*>(l)[i] = lv;
}

// ---------------------------------------------------------------------------
// Split-bf16 MFMA GEMM: C = A @ W^T + bias (optionally * scale).
// PASSES==3: AhBh + AhBl + AlBh (Q,K proj — exp-sensitive). LDS 64 KB.
// PASSES==2: AhBh + AlBh (V/out proj). LDS 48 KB.
// EPI: 0 = head-layout bf16 hi/lo ; 1 = transposed Vt **fp16** ; 2 = fp32.
// ---------------------------------------------------------------------------
template <int EPI, int PASSES>
__global__ __launch_bounds__(256, 2) void gemm3p_k(
    const __bf16* __restrict__ AH, const __bf16* __restrict__ AL,
    const __bf16* __restrict__ BH, const __bf16* __restrict__ BL,
    const float* __restrict__ bias, const float scale, __bf16* __restrict__ CH,
    __bf16* __restrict__ CL, float* __restrict__ CF) {
  __shared__ __bf16 smem[(PASSES == 3) ? 32768 : 24576];

  const int tid = threadIdx.x;
  const int lane = tid & 63;
  const int w = tid >> 6;
  const int fr = lane & 15;
  const int g = lane >> 4;
  const int wm = w >> 1, wn = w & 1;
  const int m0 = blockIdx.x << 7;
  const int n0 = blockIdx.y << 7;

#define GSTAGE(buf, kt)                                                       \
  do {                                                                        \
    const int ke_ = (kt) * 32 + (lane & 3) * 8;                               \
    _Pragma("unroll") for (int c_ = 0; c_ < 2; ++c_) {                        \
      const int rr_ = 32 * w + 16 * c_ + (lane >> 2);                         \
      const int lo_ = (32 * w + 16 * c_) * 32;                                \
      load_lds16(AH + (size_t)(m0 + rr_) * HDIM + ke_, &smem[(buf)*4096 + lo_]); \
      load_lds16(AL + (size_t)(m0 + rr_) * HDIM + ke_, &smem[8192 + (buf)*4096 + lo_]); \
      load_lds16(BH + (size_t)(n0 + rr_) * HDIM + ke_, &smem[16384 + (buf)*4096 + lo_]); \
      if (PASSES == 3)                                                        \
        load_lds16(BL + (size_t)(n0 + rr_) * HDIM + ke_, &smem[24576 + (buf)*4096 + lo_]); \
    }                                                                         \
  } while (0)

  f32x4 acc[4][4] = {};

  GSTAGE(0, 0);
  __syncthreads();

  for (int kt = 0; kt < HDIM / 32; ++kt) {
    const int buf = kt & 1;
    if (kt + 1 < HDIM / 32) GSTAGE(buf ^ 1, kt + 1);

    s16x8 aH[4], aL[4], bH[4], bL[4];
#pragma unroll
    for (int mi = 0; mi < 4; ++mi) {
      const int off = (wm * 64 + mi * 16 + fr) * 32 + g * 8;
      aH[mi] = *reinterpret_cast<const s16x8*>(&smem[buf * 4096 + off]);
      aL[mi] = *reinterpret_cast<const s16x8*>(&smem[8192 + buf * 4096 + off]);
    }
#pragma unroll
    for (int ni = 0; ni < 4; ++ni) {
      const int off = (wn * 64 + ni * 16 + fr) * 32 + g * 8;
      bH[ni] = *reinterpret_cast<const s16x8*>(&smem[16384 + buf * 4096 + off]);
      if (PASSES == 3)
        bL[ni] = *reinterpret_cast<const s16x8*>(&smem[24576 + buf * 4096 + off]);
    }
#pragma unroll
    for (int mi = 0; mi < 4; ++mi)
#pragma unroll
      for (int ni = 0; ni < 4; ++ni) {
        acc[mi][ni] = MFMA16(aH[mi], bH[ni], acc[mi][ni]);
        if (PASSES == 3) acc[mi][ni] = MFMA16(aH[mi], bL[ni], acc[mi][ni]);
        acc[mi][ni] = MFMA16(aL[mi], bH[ni], acc[mi][ni]);
      }
    __syncthreads();
  }

  float bv[4];
#pragma unroll
  for (int ni = 0; ni < 4; ++ni) bv[ni] = bias[n0 + wn * 64 + ni * 16 + fr];

  if (EPI == 0) {  // head layout [B,NH,S,HD], bf16 hi/lo, scaled
#pragma unroll
    for (int mi = 0; mi < 4; ++mi)
#pragma unroll
      for (int ni = 0; ni < 4; ++ni)
#pragma unroll
        for (int r = 0; r < 4; ++r) {
          const float v = (acc[mi][ni][r] + bv[ni]) * scale;
          const int m = m0 + wm * 64 + mi * 16 + 4 * g + r;
          const int n = n0 + wn * 64 + ni * 16 + fr;
          const int b = m >> 11, s = m & 2047, h = n >> 6, d = n & 63;
          const size_t o = ((size_t)(b * NHEAD + h) * SEQLEN + s) * HEADD + d;
          const __bf16 hb = (__bf16)v;
          CH[o] = hb;
          CL[o] = (__bf16)(v - (float)hb);
        }
  } else if (EPI == 2) {  // plain fp32 [M][H]
#pragma unroll
    for (int mi = 0; mi < 4; ++mi)
#pragma unroll
      for (int ni = 0; ni < 4; ++ni)
#pragma unroll
        for (int r = 0; r < 4; ++r) {
          const int m = m0 + wm * 64 + mi * 16 + 4 * g + r;
          const int n = n0 + wn * 64 + ni * 16 + fr;
          CF[(size_t)m * HDIM + n] = acc[mi][ni][r] + bv[ni];
        }
  } else {  // EPI == 1: transposed Vt [B,NH,HD,S] **fp16** via LDS transpose
    __syncthreads();
    short* sm = reinterpret_cast<short*>(smem);
#pragma unroll
    for (int mi = 0; mi < 4; ++mi)
#pragma unroll
      for (int ni = 0; ni < 4; ++ni)
#pragma unroll
        for (int r = 0; r < 4; ++r) {
          const float v = acc[mi][ni][r] + bv[ni];
          const int nl = wn * 64 + ni * 16 + fr;
          const int ml = wm * 64 + mi * 16 + 4 * g + r;
          sm[nl * 128 + (((ml >> 3) ^ (nl & 7)) << 3) + (ml & 7)] =
              __builtin_bit_cast(short, (_Float16)v);
        }
    __syncthreads();
    const int nl = tid >> 1, mh = tid & 1;
    const int b = m0 >> 11, s0 = m0 & 2047;
    const int gn = n0 + nl, h = gn >> 6, d = gn & 63;
#pragma unroll
    for (int j = 0; j < 8; ++j) {
      const int cm = mh * 8 + j;
      s16x8 vv = *reinterpret_cast<const s16x8*>(&sm[nl * 128 + ((cm ^ (nl & 7)) << 3)]);
      const size_t o = ((size_t)((b * NHEAD + h) * HEADD + d)) * SEQLEN + s0 + cm * 8;
      *reinterpret_cast<s16x8*>(&CH[o]) = vv;
    }
  }
#undef GSTAGE
}

// ---------------------------------------------------------------------------
// Flash attention v6: lane-local PV (key-permuted swapped QK^T), conflict-free
// K swizzle s(row)=((row>>3)&1)<<2 | (row&3) (bijective per 8-lane group),
// fp16 V + fp16 P via mfma_f32_16x16x32_f16, LDS-bounce coalesced epilogue.
// LDS: KH|KL|V dbuf = 48 KB -> 3 blocks/CU.
// ---------------------------------------------------------------------------
__global__ __launch_bounds__(256, 3) void attn8_k(
    const __bf16* __restrict__ QH, const __bf16* __restrict__ QL,
    const __bf16* __restrict__ KH, const __bf16* __restrict__ KL,
    const __bf16* __restrict__ VT, __bf16* __restrict__ OH,
    __bf16* __restrict__ OL) {
  __shared__ __bf16 smem[24576];  // 48 KB

  const int tid = threadIdx.x;
  const int lane = tid & 63;
  const int w = tid >> 6;
  const int fr = lane & 15;
  const int g = lane >> 4;
  const int f7 = fr & 7;

  // XCD swizzle: concurrent blocks on one XCD share few bh (KV L2 locality)
  const int blk = blockIdx.x;
  const int xcd = blk & 7, idx = blk >> 3;  // grid = 1024
  const int bh = xcd * 8 + (idx >> 4);      // 64 bh
  const int qt = idx & 15;                  // 16 q-tiles of 128
  const int q0 = qt << 7;
  const size_t bhO = (size_t)bh * SEQLEN * HEADD;

  // Q fragments (B-operand), pre-scaled to log2 domain by the projection.
  s16x8 qHf[2][2], qLf[2][2];
#pragma unroll
  for (int qb = 0; qb < 2; ++qb) {
    const size_t qoff = bhO + (size_t)(q0 + w * 32 + qb * 16 + fr) * HEADD;
#pragma unroll
    for (int ks = 0; ks < 2; ++ks) {
      qHf[qb][ks] = *reinterpret_cast<const s16x8*>(&QH[qoff + ks * 32 + g * 8]);
      qLf[qb][ks] = *reinterpret_cast<const s16x8*>(&QL[qoff + ks * 32 + g * 8]);
    }
  }

  // ---- loop-carried staging state (6 streams/thread) ----
  const __bf16* gsrc[6];
  int gstep[6], ldoff[6];
  {
    const int rsub = lane >> 3;
    const int l7 = lane & 7;
#pragma unroll
    for (int i_ = 0; i_ < 6; ++i_) {
      const int L_ = w * 6 + i_;
      const int t_ = L_ >> 3, sub_ = L_ & 7;
      ldoff[i_] = t_ * 8192 + sub_ * 512;
      if (t_ < 2) {
        const __bf16* base_ = (t_ == 0) ? KH : KL;
        // s(row) = ((row>>3)&1)<<2 | (row&3); row = sub_*8 + rsub
        const int ch_ = l7 ^ (((sub_ & 1) << 2) | (rsub & 3));
        gsrc[i_] = base_ + bhO + (size_t)(sub_ * 8 + rsub) * HEADD + ch_ * 8;
        gstep[i_] = 64 * HEADD;
      } else {
        const int ch_ = l7 ^ rsub;  // V: d&7 swz (unchanged)
        gsrc[i_] = VT + ((size_t)bh * HEADD + sub_ * 8 + rsub) * SEQLEN + ch_ * 8;
        gstep[i_] = 64;
      }
    }
  }

#define ASTAGE(bufl)                                              \
  do {                                                            \
    _Pragma("unroll") for (int i_ = 0; i_ < 6; ++i_) {            \
      load_lds16(gsrc[i_], &smem[ldoff[i_] + (bufl)*4096]);       \
      gsrc[i_] += gstep[i_];                                      \
    }                                                             \
  } while (0)

  // ---- precomputed LDS element-index bases ----
  // K reads (permuted rows): row kr = (kb>>1)*32 + (fr>>2)*8 + (kb&1)*4 + (fr&3)
  // slot = g ^ s(kr), s(kr) = ((fr>>2)&1)<<2 | (fr&3)  (kb-independent)
  const int sK = (((fr >> 2) & 1) << 2) | (fr & 3);
  const int rbk0 = ((fr >> 2) * 8 + (fr & 3)) * 64 + ((g ^ sK) << 3);
  const int rbk1 = rbk0 ^ 32;  // ks=1 chunk (slot^4)
  // V reads (unchanged layout)
  const int rbv0 = fr * 64 + ((g ^ f7) << 3);
  const int rbv1 = rbv0 ^ 32;

  f32x4 oacc0[4] = {}, oacc1[4] = {};
  float m0r = -1e30f, m1r = -1e30f, l0r = 0.f, l1r = 0.f;

  auto process = [&](const int B) {
    // ---- S^T = K Q^T (3-pass split); sf{qb}[kb][r] = score for
    //      key = (kb>>1)*32 + g*8 + (kb&1)*4 + r, q-col = fr ----
    f32x4 sf0[4] = {}, sf1[4] = {};
    __builtin_amdgcn_s_setprio(1);
#pragma unroll
    for (int kb = 0; kb < 4; ++kb) {
      const int ko = (kb & 1) * 256 + (kb >> 1) * 2048;
      const s16x8 kh0 = *reinterpret_cast<const s16x8*>(&smem[B * 4096 + ko + rbk0]);
      const s16x8 kl0 = *reinterpret_cast<const s16x8*>(&smem[8192 + B * 4096 + ko + rbk0]);
      const s16x8 kh1 = *reinterpret_cast<const s16x8*>(&smem[B * 4096 + ko + rbk1]);
      const s16x8 kl1 = *reinterpret_cast<const s16x8*>(&smem[8192 + B * 4096 + ko + rbk1]);
      sf0[kb] = MFMA16(kh0, qHf[0][0], sf0[kb]);
      sf0[kb] = MFMA16(kl0, qHf[0][0], sf0[kb]);
      sf0[kb] = MFMA16(kh0, qLf[0][0], sf0[kb]);
      sf0[kb] = MFMA16(kh1, qHf[0][1], sf0[kb]);
      sf0[kb] = MFMA16(kl1, qHf[0][1], sf0[kb]);
      sf0[kb] = MFMA16(kh1, qLf[0][1], sf0[kb]);
      sf1[kb] = MFMA16(kh0, qHf[1][0], sf1[kb]);
      sf1[kb] = MFMA16(kl0, qHf[1][0], sf1[kb]);
      sf1[kb] = MFMA16(kh0, qLf[1][0], sf1[kb]);
      sf1[kb] = MFMA16(kh1, qHf[1][1], sf1[kb]);
      sf1[kb] = MFMA16(kl1, qHf[1][1], sf1[kb]);
      sf1[kb] = MFMA16(kh1, qLf[1][1], sf1[kb]);
    }
    __builtin_amdgcn_s_setprio(0);

    // ---- online softmax (exp2 domain), lane-local ----
    float mx0 = sf0[0][0], mx1 = sf1[0][0];
#pragma unroll
    for (int kb = 0; kb < 4; ++kb)
#pragma unroll
      for (int r = 0; r < 4; ++r) {
        mx0 = fmaxf(mx0, sf0[kb][r]);
        mx1 = fmaxf(mx1, sf1[kb][r]);
      }
    mx0 = fmaxf(mx0, __shfl_xor(mx0, 16));
    mx0 = fmaxf(mx0, __shfl_xor(mx0, 32));
    mx1 = fmaxf(mx1, __shfl_xor(mx1, 16));
    mx1 = fmaxf(mx1, __shfl_xor(mx1, 32));
    const bool ok = (mx0 <= m0r + 11.5f) && (mx1 <= m1r + 11.5f);
    if (!__all(ok)) {  // rescale path (rare after warm-up)
      const float mn0 = fmaxf(m0r, mx0), mn1 = fmaxf(m1r, mx1);
      const float c0 = EXP2(m0r - mn0), c1 = EXP2(m1r - mn1);
      m0r = mn0; m1r = mn1;
      l0r *= c0; l1r *= c1;
      float cr0[4], cr1[4];
#pragma unroll
      for (int r = 0; r < 4; ++r) {
        cr0[r] = __shfl(c0, 4 * g + r);
        cr1[r] = __shfl(c1, 4 * g + r);
      }
#pragma unroll
      for (int di = 0; di < 4; ++di)
#pragma unroll
        for (int r = 0; r < 4; ++r) {
          oacc0[di][r] *= cr0[r];
          oacc1[di][r] *= cr1[r];
        }
    }
    float ps0 = 0.f, ps1 = 0.f;
#pragma unroll
    for (int kb = 0; kb < 4; ++kb)
#pragma unroll
      for (int r = 0; r < 4; ++r) {
        const float p0 = EXP2(sf0[kb][r] - m0r);
        const float p1 = EXP2(sf1[kb][r] - m1r);
        sf0[kb][r] = p0;
        sf1[kb][r] = p1;
        ps0 += p0;
        ps1 += p1;
      }
    ps0 += __shfl_xor(ps0, 16);
    ps0 += __shfl_xor(ps0, 32);
    ps1 += __shfl_xor(ps1, 16);
    ps1 += __shfl_xor(ps1, 32);
    l0r += ps0;
    l1r += ps1;

    // ---- O += P @ V : lane-local fp16 P, fp16 V ----
    __builtin_amdgcn_s_setprio(1);
#pragma unroll
    for (int ks = 0; ks < 2; ++ks) {
      f16x8 pa0, pa1;
#pragma unroll
      for (int i = 0; i < 4; ++i) {
        pa0[i]     = (_Float16)sf0[2 * ks][i];
        pa0[i + 4] = (_Float16)sf0[2 * ks + 1][i];
        pa1[i]     = (_Float16)sf1[2 * ks][i];
        pa1[i + 4] = (_Float16)sf1[2 * ks + 1][i];
      }
      const int rbv = ks ? rbv1 : rbv0;
#pragma unroll
      for (int di = 0; di < 4; ++di) {
        const s16x8 vraw = *reinterpret_cast<const s16x8*>(
            &smem[16384 + B * 4096 + di * 1024 + rbv]);
        const f16x8 vf = __builtin_bit_cast(f16x8, vraw);
        oacc0[di] = MFMA16H(pa0, vf, oacc0[di]);
        oacc1[di] = MFMA16H(pa1, vf, oacc1[di]);
      }
    }
    __builtin_amdgcn_s_setprio(0);
  };

  ASTAGE(0);
  __syncthreads();
  for (int kt = 0; kt < SEQLEN / 64 - 2; kt += 2) {
    ASTAGE(1);
    process(0);
    __syncthreads();
    ASTAGE(0);
    process(1);
    __syncthreads();
  }
  ASTAGE(1);
  process(0);
  __syncthreads();
  process(1);

  // ---- epilogue: normalize, LDS-bounce to coalesced dwordx4 stores ----
  const int b = bh >> 4, h = bh & 15;
  const float inv0 = 1.0f / l0r, inv1 = 1.0f / l1r;
  float iv0[4], iv1[4];
#pragma unroll
  for (int r = 0; r < 4; ++r) {
    iv0[r] = __shfl(inv0, 4 * g + r);
    iv1[r] = __shfl(inv1, 4 * g + r);
  }
  __syncthreads();  // all waves done with K/V LDS
  uint32_t* Lb = reinterpret_cast<uint32_t*>(smem);  // [128 rows][stride 68]
#pragma unroll
  for (int di = 0; di < 4; ++di)
#pragma unroll
    for (int r = 0; r < 4; ++r) {
      const int c = di * 16 + fr;
      {
        const float v = oacc0[di][r] * iv0[r];
        const __bf16 hb = (__bf16)v;
        const __bf16 lb = (__bf16)(v - (float)hb);
        const int lr = w * 32 + 4 * g + r;
        Lb[lr * 68 + c] = (uint32_t)(unsigned short)__builtin_bit_cast(short, hb) |
                          ((uint32_t)(unsigned short)__builtin_bit_cast(short, lb) << 16);
      }
      {
        const float v = oacc1[di][r] * iv1[r];
        const __bf16 hb = (__bf16)v;
        const __bf16 lb = (__bf16)(v - (float)hb);
        const int lr = w * 32 + 16 + 4 * g + r;
        Lb[lr * 68 + c] = (uint32_t)(unsigned short)__builtin_bit_cast(short, hb) |
                          ((uint32_t)(unsigned short)__builtin_bit_cast(short, lb) << 16);
      }
    }
  __syncthreads();
  {
    const int lr = tid >> 1;
    const int c0 = (tid & 1) * 32;
    const size_t obase = ((size_t)b * SEQLEN + q0 + lr) * HDIM + h * 64 + c0;
    uint32_t x[32];
#pragma unroll
    for (int k = 0; k < 8; ++k)
      *reinterpret_cast<uint4*>(&x[4 * k]) =
          *reinterpret_cast<const uint4*>(&Lb[lr * 68 + c0 + 4 * k]);
#pragma unroll
    for (int k = 0; k < 4; ++k) {
      uint4 hq, lq;
      hq.x = (x[8 * k + 0] & 0xffffu) | (x[8 * k + 1] << 16);
      hq.y = (x[8 * k + 2] & 0xffffu) | (x[8 * k + 3] << 16);
      hq.z = (x[8 * k + 4] & 0xffffu) | (x[8 * k + 5] << 16);
      hq.w = (x[8 * k + 6] & 0xffffu) | (x[8 * k + 7] << 16);
      lq.x = (x[8 * k + 0] >> 16) | (x[8 * k + 1] & 0xffff0000u);
      lq.y = (x[8 * k + 2] >> 16) | (x[8 * k + 3] & 0xffff0000u);
      lq.z = (x[8 * k + 4] >> 16) | (x[8 * k + 5] & 0xffff0000u);
      lq.w = (x[8 * k + 6] >> 16) | (x[8 * k + 7] & 0xffff0000u);
      *reinterpret_cast<uint4*>(&OH[obase + 8 * k]) = hq;
      *reinterpret_cast<uint4*>(&OL[obase + 8 * k]) = lq;
    }
  }
#undef ASTAGE
}

// ---------------------------------------------------------------------------
// Fused ReLU + LayerNorm over rows of 1024. One block (256 thr) per row.
// ---------------------------------------------------------------------------
__global__ __launch_bounds__(256) void relu_ln_k(const float* __restrict__ X,
                                                 const float* __restrict__ gam,
                                                 const float* __restrict__ bta,
                                                 float* __restrict__ out) {
  __shared__ float red[8];
  const int row = blockIdx.x;
  const int tid = threadIdx.x;
  const int c = tid << 2;

  const float4 v = *reinterpret_cast<const float4*>(&X[(size_t)row * HDIM + c]);
  float x[4] = {fmaxf(v.x, 0.f), fmaxf(v.y, 0.f), fmaxf(v.z, 0.f), fmaxf(v.w, 0.f)};
  float sum = x[0] + x[1] + x[2] + x[3];
  float ss = x[0] * x[0] + x[1] * x[1] + x[2] * x[2] + x[3] * x[3];
#pragma unroll
  for (int off = 1; off < 64; off <<= 1) {
    sum += __shfl_xor(sum, off);
    ss += __shfl_xor(ss, off);
  }
  const int wid = tid >> 6;
  if ((tid & 63) == 0) {
    red[wid] = sum;
    red[4 + wid] = ss;
  }
  __syncthreads();
  sum = red[0] + red[1] + red[2] + red[3];
  ss = red[4] + red[5] + red[6] + red[7];
  const float mean = sum * (1.0f / HDIM);
  const float var = ss * (1.0f / HDIM) - mean * mean;
  const float rstd = rsqrtf(var + LN_EPS);

  const float4 gv = *reinterpret_cast<const float4*>(&gam[c]);
  const float4 bv = *reinterpret_cast<const float4*>(&bta[c]);
  float4 o;
  o.x = (x[0] - mean) * rstd * gv.x + bv.x;
  o.y = (x[1] - mean) * rstd * gv.y + bv.y;
  o.z = (x[2] - mean) * rstd * gv.z + bv.z;
  o.w = (x[3] - mean) * rstd * gv.w + bv.w;
  *reinterpret_cast<float4*>(&out[(size_t)row * HDIM + c]) = o;
}

// ---------------------------------------------------------------------------
// Launch. ws (128 MB):
//  [0,16M): wts hi (qw,kw,vw,ow @2MB) + wts lo (@2MB each)
//  [16,48M): QH,QL        -> later proj fp32 (32MB)
//  [48,80M): KH,KL
//  [80,96M): Vt (fp16)
//  [96,128M): featH,featL -> later attnH,attnL
// ---------------------------------------------------------------------------
extern "C" void kernel_launch(void* const* d_in, const int* in_sizes, int n_in,
                              void* d_out, int out_size, void* d_ws, size_t ws_size,
                              hipStream_t stream) {
  const float* feat = (const float*)d_in[0];
  const float* qw = (const float*)d_in[1];
  const float* qb = (const float*)d_in[2];
  const float* kw = (const float*)d_in[3];
  const float* kb = (const float*)d_in[4];
  const float* vw = (const float*)d_in[5];
  const float* vb = (const float*)d_in[6];
  const float* ow = (const float*)d_in[7];
  const float* ob = (const float*)d_in[8];
  const float* ln_g = (const float*)d_in[9];
  const float* ln_b = (const float*)d_in[10];

  char* ws = (char*)d_ws;
  const size_t MB = 1u << 20;
  __bf16* qwH = (__bf16*)(ws + 0 * MB);
  __bf16* kwH = (__bf16*)(ws + 2 * MB);
  __bf16* vwH = (__bf16*)(ws + 4 * MB);
  __bf16* owH = (__bf16*)(ws + 6 * MB);
  __bf16* qwL = (__bf16*)(ws + 8 * MB);
  __bf16* kwL = (__bf16*)(ws + 10 * MB);
  __bf16* vwL = (__bf16*)(ws + 12 * MB);
  __bf16* owL = (__bf16*)(ws + 14 * MB);
  __bf16* QHp = (__bf16*)(ws + 16 * MB);
  __bf16* QLp = (__bf16*)(ws + 32 * MB);
  __bf16* KHp = (__bf16*)(ws + 48 * MB);
  __bf16* KLp = (__bf16*)(ws + 64 * MB);
  __bf16* VTp = (__bf16*)(ws + 80 * MB);  // fp16 bits, type-punned
  __bf16* ftH = (__bf16*)(ws + 96 * MB);
  __bf16* ftL = (__bf16*)(ws + 112 * MB);
  __bf16* atH = ftH;  // reuse after feat dead
  __bf16* atL = ftL;
  float* proj = (float*)(ws + 16 * MB);  // reuse Q region after attention

  // splits
  split_k<<<(MROWS * HDIM / 4 + 255) / 256, 256, 0, stream>>>(feat, ftH, ftL,
                                                              MROWS * HDIM / 4);
  wsplit_k<<<dim3(HDIM * HDIM / 4 / 256, 4), 256, 0, stream>>>(
      qw, kw, vw, ow, qwH, qwL, kwH, kwL, vwH, vwL, owH, owL);

  const dim3 gg(MROWS / 128, HDIM / 128);
  gemm3p_k<0, 3><<<gg, 256, 0, stream>>>(ftH, ftL, qwH, qwL, qb, QSCALE, QHp, QLp, nullptr);
  gemm3p_k<0, 3><<<gg, 256, 0, stream>>>(ftH, ftL, kwH, kwL, kb, 1.0f, KHp, KLp, nullptr);
  gemm3p_k<1, 2><<<gg, 256, 0, stream>>>(ftH, ftL, vwH, vwL, vb, 1.0f, VTp, nullptr, nullptr);

  attn8_k<<<BATCH * NHEAD * (SEQLEN / 128), 256, 0, stream>>>(QHp, QLp, KHp, KLp,
                                                              VTp, atH, atL);

  gemm3p_k<2, 2><<<gg, 256, 0, stream>>>(atH, atL, owH, owL, ob, 1.0f, nullptr,
                                         nullptr, proj);

  relu_ln_k<<<MROWS, 256, 0, stream>>>(proj, ln_g, ln_b, (float*)d_out);
}

// Round 9
// 381.930 us; speedup vs baseline: 1.1789x; 1.1789x over previous
//
#include <hip/hip_runtime.h>
#include <math.h>

#define HDIM 1024
#define NHEAD 16
#define HEADD 64
#define SEQLEN 2048
#define BATCH 4
#define MROWS (BATCH * SEQLEN)  // 8192
#define LN_EPS 1e-5f
#define QSCALE 2.8853900817779268f  // 2 * log2(e): logits in log2 units

typedef float f32x4 __attribute__((ext_vector_type(4)));
typedef _Float16 f16x8 __attribute__((ext_vector_type(8)));
typedef _Float16 f16x4 __attribute__((ext_vector_type(4)));

#define MFMA16H(a, b, c) __builtin_amdgcn_mfma_f32_16x16x32_f16((a), (b), (c), 0, 0, 0)

#if __has_builtin(__builtin_amdgcn_exp2f)
#define EXP2(x) __builtin_amdgcn_exp2f(x)
#else
#define EXP2(x) exp2f(x)
#endif

__device__ __forceinline__ void load_lds16(const void* g, void* l) {
  __builtin_amdgcn_global_load_lds((const __attribute__((address_space(1))) void*)g,
                                   (__attribute__((address_space(3))) void*)l, 16, 0, 0);
}

// ---------------------------------------------------------------------------
// fp32 -> fp16 (hi, lo) split, 4 elems/thread (feat / generic)
// ---------------------------------------------------------------------------
__global__ __launch_bounds__(256) void split_k(const float* __restrict__ src,
                                               _Float16* __restrict__ h,
                                               _Float16* __restrict__ l, int n4) {
  int i = blockIdx.x * blockDim.x + threadIdx.x;
  if (i >= n4) return;
  float4 v = reinterpret_cast<const float4*>(src)[i];
  f16x4 hv, lv;
  hv[0] = (_Float16)v.x; hv[1] = (_Float16)v.y;
  hv[2] = (_Float16)v.z; hv[3] = (_Float16)v.w;
  lv[0] = (_Float16)(v.x - (float)hv[0]);
  lv[1] = (_Float16)(v.y - (float)hv[1]);
  lv[2] = (_Float16)(v.z - (float)hv[2]);
  lv[3] = (_Float16)(v.w - (float)hv[3]);
  reinterpret_cast<f16x4*>(h)[i] = hv;
  reinterpret_cast<f16x4*>(l)[i] = lv;
}

// All 4 weight matrices -> single fp16, one launch (blockIdx.y selects).
__global__ __launch_bounds__(256) void wsplit_k(
    const float* __restrict__ w0, const float* __restrict__ w1,
    const float* __restrict__ w2, const float* __restrict__ w3,
    _Float16* __restrict__ f0, _Float16* __restrict__ f1,
    _Float16* __restrict__ f2, _Float16* __restrict__ f3) {
  const int which = blockIdx.y;
  const float* src = which == 0 ? w0 : which == 1 ? w1 : which == 2 ? w2 : w3;
  _Float16* dst = which == 0 ? f0 : which == 1 ? f1 : which == 2 ? f2 : f3;
  const int i = blockIdx.x * blockDim.x + threadIdx.x;
  float4 v = reinterpret_cast<const float4*>(src)[i];
  f16x4 hv;
  hv[0] = (_Float16)v.x; hv[1] = (_Float16)v.y;
  hv[2] = (_Float16)v.z; hv[3] = (_Float16)v.w;
  reinterpret_cast<f16x4*>(dst)[i] = hv;
}

// ---------------------------------------------------------------------------
// 2-pass fp16 MFMA GEMM: C = (AH+AL) @ B^T + bias (opt * scale).
// A: fp16 hi/lo split (error 2^-22), B: single fp16 (error 2^-11).
// 128x128 tile, BK=32, 4 waves, LDS 48 KB.
// EPI: 0 = head-layout fp16 single ; 1 = transposed Vt fp16 ; 2 = fp32.
// ---------------------------------------------------------------------------
template <int EPI>
__global__ __launch_bounds__(256, 2) void gemm2p_k(
    const _Float16* __restrict__ AH, const _Float16* __restrict__ AL,
    const _Float16* __restrict__ BW, const float* __restrict__ bias,
    const float scale, _Float16* __restrict__ C16, float* __restrict__ CF) {
  __shared__ _Float16 smem[24576];  // 48 KB

  const int tid = threadIdx.x;
  const int lane = tid & 63;
  const int w = tid >> 6;
  const int fr = lane & 15;
  const int g = lane >> 4;
  const int wm = w >> 1, wn = w & 1;
  const int m0 = blockIdx.x << 7;
  const int n0 = blockIdx.y << 7;

#define GSTAGE(buf, kt)                                                        \
  do {                                                                         \
    const int ke_ = (kt) * 32 + (lane & 3) * 8;                                \
    _Pragma("unroll") for (int c_ = 0; c_ < 2; ++c_) {                         \
      const int rr_ = 32 * w + 16 * c_ + (lane >> 2);                          \
      const int lo_ = (32 * w + 16 * c_) * 32;                                 \
      load_lds16(AH + (size_t)(m0 + rr_) * HDIM + ke_, &smem[(buf)*4096 + lo_]); \
      load_lds16(AL + (size_t)(m0 + rr_) * HDIM + ke_, &smem[8192 + (buf)*4096 + lo_]); \
      load_lds16(BW + (size_t)(n0 + rr_) * HDIM + ke_, &smem[16384 + (buf)*4096 + lo_]); \
    }                                                                          \
  } while (0)

  f32x4 acc[4][4] = {};

  GSTAGE(0, 0);
  __syncthreads();

  for (int kt = 0; kt < HDIM / 32; ++kt) {
    const int buf = kt & 1;
    if (kt + 1 < HDIM / 32) GSTAGE(buf ^ 1, kt + 1);

    f16x8 aH[4], aL[4], bF[4];
#pragma unroll
    for (int mi = 0; mi < 4; ++mi) {
      const int off = (wm * 64 + mi * 16 + fr) * 32 + g * 8;
      aH[mi] = *reinterpret_cast<const f16x8*>(&smem[buf * 4096 + off]);
      aL[mi] = *reinterpret_cast<const f16x8*>(&smem[8192 + buf * 4096 + off]);
    }
#pragma unroll
    for (int ni = 0; ni < 4; ++ni) {
      const int off = (wn * 64 + ni * 16 + fr) * 32 + g * 8;
      bF[ni] = *reinterpret_cast<const f16x8*>(&smem[16384 + buf * 4096 + off]);
    }
#pragma unroll
    for (int mi = 0; mi < 4; ++mi)
#pragma unroll
      for (int ni = 0; ni < 4; ++ni) {
        acc[mi][ni] = MFMA16H(aH[mi], bF[ni], acc[mi][ni]);
        acc[mi][ni] = MFMA16H(aL[mi], bF[ni], acc[mi][ni]);
      }
    __syncthreads();
  }

  float bv[4];
#pragma unroll
  for (int ni = 0; ni < 4; ++ni) bv[ni] = bias[n0 + wn * 64 + ni * 16 + fr];

  if (EPI == 0) {  // head layout [B,NH,S,HD], fp16 single, scaled
#pragma unroll
    for (int mi = 0; mi < 4; ++mi)
#pragma unroll
      for (int ni = 0; ni < 4; ++ni)
#pragma unroll
        for (int r = 0; r < 4; ++r) {
          const float v = (acc[mi][ni][r] + bv[ni]) * scale;
          const int m = m0 + wm * 64 + mi * 16 + 4 * g + r;
          const int n = n0 + wn * 64 + ni * 16 + fr;
          const int b = m >> 11, s = m & 2047, h = n >> 6, d = n & 63;
          const size_t o = ((size_t)(b * NHEAD + h) * SEQLEN + s) * HEADD + d;
          C16[o] = (_Float16)v;
        }
  } else if (EPI == 2) {  // plain fp32 [M][H]
#pragma unroll
    for (int mi = 0; mi < 4; ++mi)
#pragma unroll
      for (int ni = 0; ni < 4; ++ni)
#pragma unroll
        for (int r = 0; r < 4; ++r) {
          const int m = m0 + wm * 64 + mi * 16 + 4 * g + r;
          const int n = n0 + wn * 64 + ni * 16 + fr;
          CF[(size_t)m * HDIM + n] = acc[mi][ni][r] + bv[ni];
        }
  } else {  // EPI == 1: transposed Vt [B,NH,HD,S] fp16 via LDS transpose
    __syncthreads();
    short* sm = reinterpret_cast<short*>(smem);
#pragma unroll
    for (int mi = 0; mi < 4; ++mi)
#pragma unroll
      for (int ni = 0; ni < 4; ++ni)
#pragma unroll
        for (int r = 0; r < 4; ++r) {
          const float v = acc[mi][ni][r] + bv[ni];
          const int nl = wn * 64 + ni * 16 + fr;
          const int ml = wm * 64 + mi * 16 + 4 * g + r;
          sm[nl * 128 + (((ml >> 3) ^ (nl & 7)) << 3) + (ml & 7)] =
              __builtin_bit_cast(short, (_Float16)v);
        }
    __syncthreads();
    const int nl = tid >> 1, mh = tid & 1;
    const int b = m0 >> 11, s0 = m0 & 2047;
    const int gn = n0 + nl, h = gn >> 6, d = gn & 63;
#pragma unroll
    for (int j = 0; j < 8; ++j) {
      const int cm = mh * 8 + j;
      const uint4 vv = *reinterpret_cast<const uint4*>(&sm[nl * 128 + ((cm ^ (nl & 7)) << 3)]);
      const size_t o = ((size_t)((b * NHEAD + h) * HEADD + d)) * SEQLEN + s0 + cm * 8;
      *reinterpret_cast<uint4*>(&C16[o]) = vv;
    }
  }
#undef GSTAGE
}

// ---------------------------------------------------------------------------
// Flash attention v7: single-fp16 Q/K -> 1-pass QK^T; lane-local fp16 PV;
// conflict-free K swizzle; 34 KB LDS -> 4 blocks/CU; LDS-bounce epilogue
// writing fp16 hi/lo attn (feeds 2-pass out-proj).
// ---------------------------------------------------------------------------
__global__ __launch_bounds__(256, 4) void attn9_k(
    const _Float16* __restrict__ QF, const _Float16* __restrict__ KF,
    const _Float16* __restrict__ VT, _Float16* __restrict__ OH,
    _Float16* __restrict__ OL) {
  __shared__ short smem[17408];  // 34 KB ([0,16384) K/V dbuf; bounce reuses)

  const int tid = threadIdx.x;
  const int lane = tid & 63;
  const int w = tid >> 6;
  const int fr = lane & 15;
  const int g = lane >> 4;
  const int f7 = fr & 7;

  // XCD swizzle: concurrent blocks on one XCD share few bh (KV L2 locality)
  const int blk = blockIdx.x;
  const int xcd = blk & 7, idx = blk >> 3;  // grid = 1024
  const int bh = xcd * 8 + (idx >> 4);      // 64 bh
  const int qt = idx & 15;                  // 16 q-tiles of 128
  const int q0 = qt << 7;
  const size_t bhO = (size_t)bh * SEQLEN * HEADD;

  // Q fragments (B-operand), pre-scaled to log2 domain by the projection.
  f16x8 qf[2][2];
#pragma unroll
  for (int qb = 0; qb < 2; ++qb) {
    const size_t qoff = bhO + (size_t)(q0 + w * 32 + qb * 16 + fr) * HEADD;
#pragma unroll
    for (int ks = 0; ks < 2; ++ks)
      qf[qb][ks] = *reinterpret_cast<const f16x8*>(&QF[qoff + ks * 32 + g * 8]);
  }

  // ---- loop-carried staging state (4 streams/thread) ----
  const _Float16* gsrc[4];
  int gstep[4], ldoff[4];
  {
    const int rsub = lane >> 3;
    const int l7 = lane & 7;
#pragma unroll
    for (int i_ = 0; i_ < 4; ++i_) {
      const int L_ = w * 4 + i_;
      const int t_ = L_ >> 3, sub_ = L_ & 7;
      ldoff[i_] = t_ * 8192 + sub_ * 512;
      if (t_ == 0) {
        // K: s(row) = ((row>>3)&1)<<2 | (row&3); row = sub_*8 + rsub
        const int ch_ = l7 ^ (((sub_ & 1) << 2) | (rsub & 3));
        gsrc[i_] = KF + bhO + (size_t)(sub_ * 8 + rsub) * HEADD + ch_ * 8;
        gstep[i_] = 64 * HEADD;
      } else {
        const int ch_ = l7 ^ rsub;  // V: d&7 swz
        gsrc[i_] = VT + ((size_t)bh * HEADD + sub_ * 8 + rsub) * SEQLEN + ch_ * 8;
        gstep[i_] = 64;
      }
    }
  }

#define ASTAGE(bufl)                                              \
  do {                                                            \
    _Pragma("unroll") for (int i_ = 0; i_ < 4; ++i_) {            \
      load_lds16(gsrc[i_], &smem[ldoff[i_] + (bufl)*4096]);       \
      gsrc[i_] += gstep[i_];                                      \
    }                                                             \
  } while (0)

  // ---- precomputed LDS element-index bases ----
  // K reads (permuted rows): row kr = (kb>>1)*32 + (fr>>2)*8 + (kb&1)*4 + (fr&3)
  // slot = g ^ s(kr), s(kr) = ((fr>>2)&1)<<2 | (fr&3)  (kb-independent)
  const int sK = (((fr >> 2) & 1) << 2) | (fr & 3);
  const int rbk0 = ((fr >> 2) * 8 + (fr & 3)) * 64 + ((g ^ sK) << 3);
  const int rbk1 = rbk0 ^ 32;  // ks=1 chunk (slot^4)
  const int rbv0 = fr * 64 + ((g ^ f7) << 3);
  const int rbv1 = rbv0 ^ 32;

  f32x4 oacc0[4] = {}, oacc1[4] = {};
  float m0r = -1e30f, m1r = -1e30f, l0r = 0.f, l1r = 0.f;

  auto process = [&](const int B) {
    // ---- S^T = K Q^T (1-pass fp16); sf{qb}[kb][r] = score for
    //      key = (kb>>1)*32 + g*8 + (kb&1)*4 + r, q-col = fr ----
    f32x4 sf0[4] = {}, sf1[4] = {};
    __builtin_amdgcn_s_setprio(1);
#pragma unroll
    for (int kb = 0; kb < 4; ++kb) {
      const int ko = (kb & 1) * 256 + (kb >> 1) * 2048;
      const f16x8 kh0 = *reinterpret_cast<const f16x8*>(&smem[B * 4096 + ko + rbk0]);
      const f16x8 kh1 = *reinterpret_cast<const f16x8*>(&smem[B * 4096 + ko + rbk1]);
      sf0[kb] = MFMA16H(kh0, qf[0][0], sf0[kb]);
      sf0[kb] = MFMA16H(kh1, qf[0][1], sf0[kb]);
      sf1[kb] = MFMA16H(kh0, qf[1][0], sf1[kb]);
      sf1[kb] = MFMA16H(kh1, qf[1][1], sf1[kb]);
    }
    __builtin_amdgcn_s_setprio(0);

    // ---- online softmax (exp2 domain), lane-local ----
    float mx0 = sf0[0][0], mx1 = sf1[0][0];
#pragma unroll
    for (int kb = 0; kb < 4; ++kb)
#pragma unroll
      for (int r = 0; r < 4; ++r) {
        mx0 = fmaxf(mx0, sf0[kb][r]);
        mx1 = fmaxf(mx1, sf1[kb][r]);
      }
    mx0 = fmaxf(mx0, __shfl_xor(mx0, 16));
    mx0 = fmaxf(mx0, __shfl_xor(mx0, 32));
    mx1 = fmaxf(mx1, __shfl_xor(mx1, 16));
    mx1 = fmaxf(mx1, __shfl_xor(mx1, 32));
    const bool ok = (mx0 <= m0r + 11.0f) && (mx1 <= m1r + 11.0f);
    if (!__all(ok)) {  // rescale path (rare after warm-up)
      const float mn0 = fmaxf(m0r, mx0), mn1 = fmaxf(m1r, mx1);
      const float c0 = EXP2(m0r - mn0), c1 = EXP2(m1r - mn1);
      m0r = mn0; m1r = mn1;
      l0r *= c0; l1r *= c1;
      float cr0[4], cr1[4];
#pragma unroll
      for (int r = 0; r < 4; ++r) {
        cr0[r] = __shfl(c0, 4 * g + r);
        cr1[r] = __shfl(c1, 4 * g + r);
      }
#pragma unroll
      for (int di = 0; di < 4; ++di)
#pragma unroll
        for (int r = 0; r < 4; ++r) {
          oacc0[di][r] *= cr0[r];
          oacc1[di][r] *= cr1[r];
        }
    }
    float ps0 = 0.f, ps1 = 0.f;
#pragma unroll
    for (int kb = 0; kb < 4; ++kb)
#pragma unroll
      for (int r = 0; r < 4; ++r) {
        const float p0 = EXP2(sf0[kb][r] - m0r);
        const float p1 = EXP2(sf1[kb][r] - m1r);
        sf0[kb][r] = p0;
        sf1[kb][r] = p1;
        ps0 += p0;
        ps1 += p1;
      }
    ps0 += __shfl_xor(ps0, 16);
    ps0 += __shfl_xor(ps0, 32);
    ps1 += __shfl_xor(ps1, 16);
    ps1 += __shfl_xor(ps1, 32);
    l0r += ps0;
    l1r += ps1;

    // ---- O += P @ V : lane-local fp16 P, fp16 V ----
    __builtin_amdgcn_s_setprio(1);
#pragma unroll
    for (int ks = 0; ks < 2; ++ks) {
      f16x8 pa0, pa1;
#pragma unroll
      for (int i = 0; i < 4; ++i) {
        pa0[i]     = (_Float16)sf0[2 * ks][i];
        pa0[i + 4] = (_Float16)sf0[2 * ks + 1][i];
        pa1[i]     = (_Float16)sf1[2 * ks][i];
        pa1[i + 4] = (_Float16)sf1[2 * ks + 1][i];
      }
      const int rbv = ks ? rbv1 : rbv0;
#pragma unroll
      for (int di = 0; di < 4; ++di) {
        const f16x8 vf = *reinterpret_cast<const f16x8*>(
            &smem[8192 + B * 4096 + di * 1024 + rbv]);
        oacc0[di] = MFMA16H(pa0, vf, oacc0[di]);
        oacc1[di] = MFMA16H(pa1, vf, oacc1[di]);
      }
    }
    __builtin_amdgcn_s_setprio(0);
  };

  ASTAGE(0);
  __syncthreads();
  for (int kt = 0; kt < SEQLEN / 64 - 2; kt += 2) {
    ASTAGE(1);
    process(0);
    __syncthreads();
    ASTAGE(0);
    process(1);
    __syncthreads();
  }
  ASTAGE(1);
  process(0);
  __syncthreads();
  process(1);

  // ---- epilogue: normalize, LDS-bounce to coalesced dwordx4 stores ----
  const int b = bh >> 4, h = bh & 15;
  const float inv0 = 1.0f / l0r, inv1 = 1.0f / l1r;
  float iv0[4], iv1[4];
#pragma unroll
  for (int r = 0; r < 4; ++r) {
    iv0[r] = __shfl(inv0, 4 * g + r);
    iv1[r] = __shfl(inv1, 4 * g + r);
  }
  __syncthreads();  // all waves done with K/V LDS
  uint32_t* Lb = reinterpret_cast<uint32_t*>(smem);  // [128 rows][stride 68]
#pragma unroll
  for (int di = 0; di < 4; ++di)
#pragma unroll
    for (int r = 0; r < 4; ++r) {
      const int c = di * 16 + fr;
      {
        const float v = oacc0[di][r] * iv0[r];
        const _Float16 hb = (_Float16)v;
        const _Float16 lb = (_Float16)(v - (float)hb);
        const int lr = w * 32 + 4 * g + r;
        Lb[lr * 68 + c] = (uint32_t)(unsigned short)__builtin_bit_cast(short, hb) |
                          ((uint32_t)(unsigned short)__builtin_bit_cast(short, lb) << 16);
      }
      {
        const float v = oacc1[di][r] * iv1[r];
        const _Float16 hb = (_Float16)v;
        const _Float16 lb = (_Float16)(v - (float)hb);
        const int lr = w * 32 + 16 + 4 * g + r;
        Lb[lr * 68 + c] = (uint32_t)(unsigned short)__builtin_bit_cast(short, hb) |
                          ((uint32_t)(unsigned short)__builtin_bit_cast(short, lb) << 16);
      }
    }
  __syncthreads();
  {
    const int lr = tid >> 1;
    const int c0 = (tid & 1) * 32;
    const size_t obase = ((size_t)b * SEQLEN + q0 + lr) * HDIM + h * 64 + c0;
    uint32_t x[32];
#pragma unroll
    for (int k = 0; k < 8; ++k)
      *reinterpret_cast<uint4*>(&x[4 * k]) =
          *reinterpret_cast<const uint4*>(&Lb[lr * 68 + c0 + 4 * k]);
#pragma unroll
    for (int k = 0; k < 4; ++k) {
      uint4 hq, lq;
      hq.x = (x[8 * k + 0] & 0xffffu) | (x[8 * k + 1] << 16);
      hq.y = (x[8 * k + 2] & 0xffffu) | (x[8 * k + 3] << 16);
      hq.z = (x[8 * k + 4] & 0xffffu) | (x[8 * k + 5] << 16);
      hq.w = (x[8 * k + 6] & 0xffffu) | (x[8 * k + 7] << 16);
      lq.x = (x[8 * k + 0] >> 16) | (x[8 * k + 1] & 0xffff0000u);
      lq.y = (x[8 * k + 2] >> 16) | (x[8 * k + 3] & 0xffff0000u);
      lq.z = (x[8 * k + 4] >> 16) | (x[8 * k + 5] & 0xffff0000u);
      lq.w = (x[8 * k + 6] >> 16) | (x[8 * k + 7] & 0xffff0000u);
      *reinterpret_cast<uint4*>(&OH[obase + 8 * k]) = hq;
      *reinterpret_cast<uint4*>(&OL[obase + 8 * k]) = lq;
    }
  }
#undef ASTAGE
}

// ---------------------------------------------------------------------------
// Fused ReLU + LayerNorm over rows of 1024. One block (256 thr) per row.
// ---------------------------------------------------------------------------
__global__ __launch_bounds__(256) void relu_ln_k(const float* __restrict__ X,
                                                 const float* __restrict__ gam,
                                                 const float* __restrict__ bta,
                                                 float* __restrict__ out) {
  __shared__ float red[8];
  const int row = blockIdx.x;
  const int tid = threadIdx.x;
  const int c = tid << 2;

  const float4 v = *reinterpret_cast<const float4*>(&X[(size_t)row * HDIM + c]);
  float x[4] = {fmaxf(v.x, 0.f), fmaxf(v.y, 0.f), fmaxf(v.z, 0.f), fmaxf(v.w, 0.f)};
  float sum = x[0] + x[1] + x[2] + x[3];
  float ss = x[0] * x[0] + x[1] * x[1] + x[2] * x[2] + x[3] * x[3];
#pragma unroll
  for (int off = 1; off < 64; off <<= 1) {
    sum += __shfl_xor(sum, off);
    ss += __shfl_xor(ss, off);
  }
  const int wid = tid >> 6;
  if ((tid & 63) == 0) {
    red[wid] = sum;
    red[4 + wid] = ss;
  }
  __syncthreads();
  sum = red[0] + red[1] + red[2] + red[3];
  ss = red[4] + red[5] + red[6] + red[7];
  const float mean = sum * (1.0f / HDIM);
  const float var = ss * (1.0f / HDIM) - mean * mean;
  const float rstd = rsqrtf(var + LN_EPS);

  const float4 gv = *reinterpret_cast<const float4*>(&gam[c]);
  const float4 bv = *reinterpret_cast<const float4*>(&bta[c]);
  float4 o;
  o.x = (x[0] - mean) * rstd * gv.x + bv.x;
  o.y = (x[1] - mean) * rstd * gv.y + bv.y;
  o.z = (x[2] - mean) * rstd * gv.z + bv.z;
  o.w = (x[3] - mean) * rstd * gv.w + bv.w;
  *reinterpret_cast<float4*>(&out[(size_t)row * HDIM + c]) = o;
}

// ---------------------------------------------------------------------------
// Launch. ws (128 MB), all fp16:
//  [0,8M): qwF,kwF,vwF,owF (2MB each)
//  [16,32M): QF   -\
//  [32,48M): KF   --> after attn: proj fp32 [16,48M)
//  [48,64M): VT
//  [64,96M): ftH, ftL
//  [96,128M): atH, atL
// ---------------------------------------------------------------------------
extern "C" void kernel_launch(void* const* d_in, const int* in_sizes, int n_in,
                              void* d_out, int out_size, void* d_ws, size_t ws_size,
                              hipStream_t stream) {
  const float* feat = (const float*)d_in[0];
  const float* qw = (const float*)d_in[1];
  const float* qb = (const float*)d_in[2];
  const float* kw = (const float*)d_in[3];
  const float* kb = (const float*)d_in[4];
  const float* vw = (const float*)d_in[5];
  const float* vb = (const float*)d_in[6];
  const float* ow = (const float*)d_in[7];
  const float* ob = (const float*)d_in[8];
  const float* ln_g = (const float*)d_in[9];
  const float* ln_b = (const float*)d_in[10];

  char* ws = (char*)d_ws;
  const size_t MB = 1u << 20;
  _Float16* qwF = (_Float16*)(ws + 0 * MB);
  _Float16* kwF = (_Float16*)(ws + 2 * MB);
  _Float16* vwF = (_Float16*)(ws + 4 * MB);
  _Float16* owF = (_Float16*)(ws + 6 * MB);
  _Float16* QFp = (_Float16*)(ws + 16 * MB);
  _Float16* KFp = (_Float16*)(ws + 32 * MB);
  _Float16* VTp = (_Float16*)(ws + 48 * MB);
  _Float16* ftH = (_Float16*)(ws + 64 * MB);
  _Float16* ftL = (_Float16*)(ws + 80 * MB);
  _Float16* atH = (_Float16*)(ws + 96 * MB);
  _Float16* atL = (_Float16*)(ws + 112 * MB);
  float* proj = (float*)(ws + 16 * MB);  // reuse Q/K region after attention

  // splits
  split_k<<<(MROWS * HDIM / 4 + 255) / 256, 256, 0, stream>>>(feat, ftH, ftL,
                                                              MROWS * HDIM / 4);
  wsplit_k<<<dim3(HDIM * HDIM / 4 / 256, 4), 256, 0, stream>>>(qw, kw, vw, ow,
                                                               qwF, kwF, vwF, owF);

  const dim3 gg(MROWS / 128, HDIM / 128);
  gemm2p_k<0><<<gg, 256, 0, stream>>>(ftH, ftL, qwF, qb, QSCALE, QFp, nullptr);
  gemm2p_k<0><<<gg, 256, 0, stream>>>(ftH, ftL, kwF, kb, 1.0f, KFp, nullptr);
  gemm2p_k<1><<<gg, 256, 0, stream>>>(ftH, ftL, vwF, vb, 1.0f, VTp, nullptr);

  attn9_k<<<BATCH * NHEAD * (SEQLEN / 128), 256, 0, stream>>>(QFp, KFp, VTp, atH, atL);

  gemm2p_k<2><<<gg, 256, 0, stream>>>(atH, atL, owF, ob, 1.0f, nullptr, proj);

  relu_ln_k<<<MROWS, 256, 0, stream>>>(proj, ln_g, ln_b, (float*)d_out);
}